// Round 15
// baseline (296.863 us; speedup 1.0000x reference)
//
#include <hip/hip_runtime.h>

#define T_STEPS 100
#define BATCH   512
#define FIN     784
#define O1      100
#define O2      10
#define NC1     28      // 28 chunks of K=28

typedef __attribute__((ext_vector_type(4))) double f64x4;

// ---------------------------------------------------------------------------
// K1 v14: fused C-mean + f64 MFMA GEMM — barrier-free, per-wave LDS,
// DEPTH-2 register pipelines on BOTH operand streams.
//   I1T[t][o][b] = sum_f 0.5*(in[b,t,f,0]+in[b,t,f,1]) * W1[f,o]
// v13 post-mortem: pipe runs at spec 16cy/MFMA when fed (util x dur = 116us
// in EVERY round) but W lead (~150cy) < L1 latency (~200cy) and ist lead
// (~850cy) < HBM latency (~900cy) -> ~300-800cy stall per 784cy of MFMA.
// v14: ping-pong istA/istB and wA/wB (static names, rule #20), loop
// unrolled x2 -> every load issued ~2 chunks (~1600cy) before consumption.
// Steady state per chunk: compute(c) -> issue W(c+2) -> ds_write(c+1)
// -> issue ist(c+3). Zero barriers; own-wave lgkmcnt orders LDS RAW.
// o-tiles {0,16,32,48,64,80,84}; 84 overlaps 80 -> duplicate stores bitwise
// identical. Grid (8,100) = 800 blocks x 4 waves.
// ---------------------------------------------------------------------------
__global__ __launch_bounds__(256) void k1_mfma(const float* __restrict__ in,
                                               const float* __restrict__ W1,
                                               double* __restrict__ I1T) {
  __shared__ double AI[2][4][NC1][17];   // [buf][wave][f-in-chunk][b-row] 30.6 KB
  const int tid = threadIdx.x;
  const int l   = tid & 63;
  const int w   = tid >> 6;
  const int r16 = l & 15;
  const int q16 = l >> 4;
  const int b0  = (int)blockIdx.x * 64 + w * 16;  // wave's 16-row group
  const int t   = (int)blockIdx.y;

  // --- staging descriptors: 224 float4 per wave (16 rows x 14) over 64 lanes
  bool iact[4]; int irow[4], iq[4]; const float* ibp[4];
#pragma unroll
  for (int p = 0; p < 4; ++p) {
    const int i = p * 64 + l;
    iact[p] = (i < 224);
    const int row = iact[p] ? i / 14 : 0;
    iq[p]   = (iact[p] ? i : 0) - row * 14;
    irow[p] = row;
    ibp[p]  = in + ((size_t)(b0 + row) * T_STEPS + t) * (FIN * 2) + iq[p] * 4;
  }

  // --- in-kernel D-layout probe (validated rounds 3-14) ---
  const f64x4 z = {0.0, 0.0, 0.0, 0.0};
  f64x4 pr = __builtin_amdgcn_mfma_f64_16x16x4f64((double)r16, 0.25, z, 0, 0, 0);
  f64x4 pc = __builtin_amdgcn_mfma_f64_16x16x4f64(0.25, (double)r16, z, 0, 0, 0);
  int soff0, soff1, soff2, soff3;
  {
    int rm0 = (int)(pr[0] + 0.5), cm0 = (int)(pc[0] + 0.5);
    int rm1 = (int)(pr[1] + 0.5), cm1 = (int)(pc[1] + 0.5);
    int rm2 = (int)(pr[2] + 0.5), cm2 = (int)(pc[2] + 0.5);
    int rm3 = (int)(pr[3] + 0.5), cm3 = (int)(pc[3] + 0.5);
    soff0 = rm0 * BATCH + cm0; soff1 = rm1 * BATCH + cm1;
    soff2 = rm2 * BATCH + cm2; soff3 = rm3 * BATCH + cm3;
  }

  // W source: lane (q16, r16) reads W1[(28c + 4q + q16)*100 + o_n + r16]
  const float* pW = W1 + (size_t)q16 * O1 + r16;

  f64x4 A0 = z, A1 = z, A2 = z, A3 = z, A4 = z, A5 = z, A6 = z;

#define ISSUE_IST(DST, C)                                                  \
  _Pragma("unroll")                                                        \
  for (int p = 0; p < 4; ++p)                                              \
    if (iact[p]) DST[p] = *reinterpret_cast<const float4*>(ibp[p] + (C) * 56);
#define ISSUE_W(DST, C)                                                    \
  {                                                                        \
    const float* pWc = pW + (size_t)(C) * (28 * O1);                       \
    _Pragma("unroll")                                                      \
    for (int q = 0; q < 7; ++q) {                                          \
      const float* pw = pWc + (size_t)q * 400;                             \
      DST[q][0] = pw[0];  DST[q][1] = pw[16]; DST[q][2] = pw[32];          \
      DST[q][3] = pw[48]; DST[q][4] = pw[64]; DST[q][5] = pw[80];          \
      DST[q][6] = pw[84];                                                  \
    }                                                                      \
  }
#define DSW(BUF, SRC)                                                      \
  _Pragma("unroll")                                                        \
  for (int p = 0; p < 4; ++p)                                              \
    if (iact[p]) {                                                         \
      AI[BUF][w][iq[p] * 2 + 0][irow[p]] =                                 \
          0.5 * ((double)SRC[p].x + (double)SRC[p].y);                     \
      AI[BUF][w][iq[p] * 2 + 1][irow[p]] =                                 \
          0.5 * ((double)SRC[p].z + (double)SRC[p].w);                     \
    }
#define MF(D, Aop, Bop) D = __builtin_amdgcn_mfma_f64_16x16x4f64((Aop), (Bop), (D), 0, 0, 0)
#define COMPUTE(BUF, WS)                                                   \
  _Pragma("unroll")                                                        \
  for (int q = 0; q < 7; ++q) {                                            \
    const double bv = AI[BUF][w][q * 4 + q16][r16];                        \
    MF(A0, (double)WS[q][0], bv); MF(A1, (double)WS[q][1], bv);            \
    MF(A2, (double)WS[q][2], bv); MF(A3, (double)WS[q][3], bv);            \
    MF(A4, (double)WS[q][4], bv); MF(A5, (double)WS[q][5], bv);            \
    MF(A6, (double)WS[q][6], bv);                                          \
  }

  float4 istA[4], istB[4];
  float  wA[7][7], wB[7][7];

  // prologue: 2-deep leads on both streams
  ISSUE_IST(istA, 0);
  ISSUE_IST(istB, 1);
  ISSUE_W(wA, 0);
  ISSUE_W(wB, 1);
  DSW(0, istA);          // waits vmcnt for istA only (oldest)
  ISSUE_IST(istA, 2);

  for (int cc = 0; cc < 14; ++cc) {
    const int c0 = 2 * cc, c1 = c0 + 1;
    // --- chunk c0: buf0 + wA ---
    COMPUTE(0, wA);                 // lgkm orders ds_write(buf0); wA landed long ago
    if (c0 + 2 < NC1) ISSUE_W(wA, c0 + 2);
    DSW(1, istB);                   // waits istB (issued 2 chunks ago)
    if (c1 + 2 < NC1) ISSUE_IST(istB, c1 + 2);
    // --- chunk c1: buf1 + wB ---
    COMPUTE(1, wB);
    if (c0 + 3 < NC1) ISSUE_W(wB, c0 + 3);
    if (c0 + 2 < NC1) { DSW(0, istA); }   // waits istA (issued 2 chunks ago)
    if (c0 + 4 < NC1) ISSUE_IST(istA, c0 + 4);
  }
#undef COMPUTE
#undef MF
#undef DSW
#undef ISSUE_W
#undef ISSUE_IST

  // epilogue: 7 static tile stores through the probed D map
  double* base = I1T + ((size_t)t * O1) * BATCH + b0;
#define ST(ACC, O0)                                                        \
  {                                                                        \
    base[(size_t)(O0) * BATCH + soff0] = (ACC)[0];                         \
    base[(size_t)(O0) * BATCH + soff1] = (ACC)[1];                         \
    base[(size_t)(O0) * BATCH + soff2] = (ACC)[2];                         \
    base[(size_t)(O0) * BATCH + soff3] = (ACC)[3];                         \
  }
  ST(A0, 0); ST(A1, 16); ST(A2, 32); ST(A3, 48);
  ST(A4, 64); ST(A5, 80); ST(A6, 84);
#undef ST
}

// ---------------------------------------------------------------------------
// K2: BN stats per (t,o) row: mu, rstd. One wave per row.
// ---------------------------------------------------------------------------
__global__ __launch_bounds__(256) void k2_bnstats(const double* __restrict__ I1T,
                                                  double* __restrict__ mu,
                                                  double* __restrict__ rstd) {
  const int r    = blockIdx.x * 4 + (threadIdx.x >> 6);
  const int lane = threadIdx.x & 63;
  const double2* row2 = reinterpret_cast<const double2*>(I1T + (size_t)r * BATCH) + lane * 4;
  double v[8];
#pragma unroll
  for (int u = 0; u < 4; ++u) {
    double2 p = row2[u];
    v[2 * u] = p.x; v[2 * u + 1] = p.y;
  }
  double s = 0.0;
#pragma unroll
  for (int u = 0; u < 8; ++u) s += v[u];
#pragma unroll
  for (int m = 32; m >= 1; m >>= 1) s += __shfl_xor(s, m, 64);
  const double mean = s / 512.0;
  double q = 0.0;
#pragma unroll
  for (int u = 0; u < 8; ++u) { double d = v[u] - mean; q += d * d; }
#pragma unroll
  for (int m = 32; m >= 1; m >>= 1) q += __shfl_xor(q, m, 64);
  if (lane == 0) {
    mu[r]   = mean;
    rstd[r] = 1.0 / sqrt(q / 512.0 + 1e-5);
  }
}

// ---------------------------------------------------------------------------
// K3: layer-1 LIF scan. Block = o, thread = b.
// ---------------------------------------------------------------------------
__global__ __launch_bounds__(512) void k3_lif1(const double* __restrict__ I1T,
                                               const double* __restrict__ mu,
                                               const double* __restrict__ rstd,
                                               const float* __restrict__ scale,
                                               const float* __restrict__ bias,
                                               float* __restrict__ z1T) {
  const int o = blockIdx.x;
  const int b = threadIdx.x;
  const double sc = (double)scale[o], bs = (double)bias[o];
  double v = 0.0;
  for (int tc = 0; tc < T_STEPS; tc += 10) {
    double x[10], muv[10], rsv[10];
#pragma unroll
    for (int u = 0; u < 10; ++u) {
      const int t = tc + u;
      x[u]   = I1T[((size_t)t * O1 + o) * BATCH + b];
      muv[u] = mu[t * O1 + o];
      rsv[u] = rstd[t * O1 + o];
    }
#pragma unroll
    for (int u = 0; u < 10; ++u) {
      const double i = ((x[u] - muv[u]) * rsv[u]) * sc + bs;
      v = 0.95 * v + i;
      const bool z = (v > 1.0);
      z1T[((size_t)(tc + u) * O1 + o) * BATCH + b] = z ? 1.0f : 0.0f;
      if (z) v = 0.0;
    }
  }
}

// ---------------------------------------------------------------------------
// K4: I2[t][j][b] = sum_o z1T[t][o][b] * W2[o][j].
// ---------------------------------------------------------------------------
__global__ __launch_bounds__(512) void k4_proj2(const float* __restrict__ z1T,
                                                const float* __restrict__ W2,
                                                double* __restrict__ I2) {
  __shared__ double W2_lds[O1 * O2];
  const int t = blockIdx.x;
  const int b = threadIdx.x;
  for (int i = threadIdx.x; i < O1 * O2; i += 512) W2_lds[i] = (double)W2[i];
  __syncthreads();
  double acc[O2];
#pragma unroll
  for (int j = 0; j < O2; ++j) acc[j] = 0.0;
  for (int o = 0; o < O1; ++o) {
    const double z = (double)z1T[((size_t)t * O1 + o) * BATCH + b];
#pragma unroll
    for (int j = 0; j < O2; ++j) acc[j] += z * W2_lds[o * O2 + j];
  }
#pragma unroll
  for (int j = 0; j < O2; ++j)
    I2[((size_t)t * O2 + j) * BATCH + b] = acc[j];
}

// ---------------------------------------------------------------------------
// K5: layer-2 LIF scan + time-mean.
// ---------------------------------------------------------------------------
__global__ __launch_bounds__(512) void k5_lif2(const double* __restrict__ I2,
                                               float* __restrict__ out) {
  const int j = blockIdx.x;
  const int b = threadIdx.x;
  double v = 0.0;
  int cnt = 0;
  for (int tc = 0; tc < T_STEPS; tc += 10) {
    double x[10];
#pragma unroll
    for (int u = 0; u < 10; ++u)
      x[u] = I2[((size_t)(tc + u) * O2 + j) * BATCH + b];
#pragma unroll
    for (int u = 0; u < 10; ++u) {
      v = 0.95 * v + x[u];
      if (v > 1.0) { ++cnt; v = 0.0; }
    }
  }
  out[b * O2 + j] = (float)((double)cnt / 100.0);
}

// ---------------------------------------------------------------------------
extern "C" void kernel_launch(void* const* d_in, const int* in_sizes, int n_in,
                              void* d_out, int out_size, void* d_ws, size_t ws_size,
                              hipStream_t stream) {
  const float* in    = (const float*)d_in[0];
  const float* W1    = (const float*)d_in[2];
  const float* scale = (const float*)d_in[3];
  const float* bias  = (const float*)d_in[4];
  const float* W2    = (const float*)d_in[5];
  float* out = (float*)d_out;

  char* ws = (char*)d_ws;
  size_t off = 0;
  double* I1T  = (double*)(ws + off); off += (size_t)T_STEPS * O1 * BATCH * sizeof(double);
  double* mu   = (double*)(ws + off); off += (size_t)T_STEPS * O1 * sizeof(double);
  double* rstd = (double*)(ws + off); off += (size_t)T_STEPS * O1 * sizeof(double);
  float*  z1T  = (float*)(ws + off);  off += (size_t)T_STEPS * O1 * BATCH * sizeof(float);
  double* I2   = (double*)(ws + off); off += (size_t)T_STEPS * O2 * BATCH * sizeof(double);

  k1_mfma   <<<dim3(BATCH / 64, T_STEPS), 256, 0, stream>>>(in, W1, I1T);
  k2_bnstats<<<dim3(T_STEPS * O1 / 4), 256, 0, stream>>>(I1T, mu, rstd);
  k3_lif1   <<<dim3(O1), 512, 0, stream>>>(I1T, mu, rstd, scale, bias, z1T);
  k4_proj2  <<<dim3(T_STEPS), 512, 0, stream>>>(z1T, W2, I2);
  k5_lif2   <<<dim3(O2), 512, 0, stream>>>(I2, out);
}